// Round 4
// baseline (797.135 us; speedup 1.0000x reference)
//
#include <hip/hip_runtime.h>
#include <hip/hip_bf16.h>
#include <hip/hip_fp16.h>

#define L_SEQ 16384
#define HDIM  1024
#define CH    32
#define NC    (L_SEQ / CH)   // 512 chunks

typedef _Float16 f16;
typedef _Float16 f16x8 __attribute__((ext_vector_type(8)));
typedef _Float16 f16x4 __attribute__((ext_vector_type(4)));
typedef float    f32x4 __attribute__((ext_vector_type(4)));

#define AS1(p) (const __attribute__((address_space(1))) void*)(p)
#define AS3(p) (__attribute__((address_space(3))) void*)(p)

// -------- weight convert + transpose: out[n*K+k] = (f16) in[k*N+n] --------
__global__ __launch_bounds__(256) void wcvt_t(const float* __restrict__ in,
                                              f16* __restrict__ out, int K, int N) {
  __shared__ float tile[32][33];
  int n0 = blockIdx.x * 32, k0 = blockIdx.y * 32;
  int tx = threadIdx.x, ty = threadIdx.y;  // (32,8)
#pragma unroll
  for (int i = 0; i < 4; i++) {
    int k = k0 + ty + i * 8;
    tile[ty + i * 8][tx] = in[(size_t)k * N + n0 + tx];
  }
  __syncthreads();
#pragma unroll
  for (int i = 0; i < 4; i++) {
    int n = n0 + ty + i * 8;
    out[(size_t)n * K + k0 + tx] = (f16)tile[tx][ty + i * 8];
  }
}

// -------- LayerNorm fp32 in -> f16 out (+ optional f16 copy of input) -----
__global__ __launch_bounds__(256) void ln_k(const float* __restrict__ x,
                                            const float* __restrict__ w,
                                            const float* __restrict__ b,
                                            f16* __restrict__ out,
                                            f16* __restrict__ xcopy) {
  int row = blockIdx.x;
  int t = threadIdx.x;
  const float4* xr = (const float4*)(x + (size_t)row * HDIM);
  float4 v = xr[t];
  float s  = v.x + v.y + v.z + v.w;
  float s2 = v.x * v.x + v.y * v.y + v.z * v.z + v.w * v.w;
#pragma unroll
  for (int off = 32; off > 0; off >>= 1) {
    s  += __shfl_down(s, off);
    s2 += __shfl_down(s2, off);
  }
  __shared__ float red[8];
  int wid = t >> 6, lane = t & 63;
  if (lane == 0) { red[wid] = s; red[4 + wid] = s2; }
  __syncthreads();
  if (t == 0) {
    red[0] = red[0] + red[1] + red[2] + red[3];
    red[4] = red[4] + red[5] + red[6] + red[7];
  }
  __syncthreads();
  float mean = red[0] * (1.0f / HDIM);
  float var  = red[4] * (1.0f / HDIM) - mean * mean;
  float rstd = rsqrtf(var + 1e-5f);
  float4 ww = ((const float4*)w)[t];
  float4 bb = ((const float4*)b)[t];
  f16x4 o;
  o[0] = (f16)((v.x - mean) * rstd * ww.x + bb.x);
  o[1] = (f16)((v.y - mean) * rstd * ww.y + bb.y);
  o[2] = (f16)((v.z - mean) * rstd * ww.z + bb.z);
  o[3] = (f16)((v.w - mean) * rstd * ww.w + bb.w);
  ((f16x4*)(out + (size_t)row * HDIM))[t] = o;
  if (xcopy) {
    f16x4 c;
    c[0] = (f16)v.x; c[1] = (f16)v.y; c[2] = (f16)v.z; c[3] = (f16)v.w;
    ((f16x4*)(xcopy + (size_t)row * HDIM))[t] = c;
  }
}

// -------- LayerNorm f16 in -> f16 out, 128 thr/row, f16x8 loads --------
__global__ __launch_bounds__(128) void ln_k16(const f16* __restrict__ x,
                                              const float* __restrict__ w,
                                              const float* __restrict__ b,
                                              f16* __restrict__ out) {
  int row = blockIdx.x;
  int t = threadIdx.x;  // 0..127
  f16x8 xv = ((const f16x8*)(x + (size_t)row * HDIM))[t];
  float v[8];
  float s = 0.f, s2 = 0.f;
#pragma unroll
  for (int i = 0; i < 8; i++) {
    v[i] = (float)xv[i];
    s += v[i]; s2 += v[i] * v[i];
  }
#pragma unroll
  for (int off = 32; off > 0; off >>= 1) {
    s  += __shfl_down(s, off);
    s2 += __shfl_down(s2, off);
  }
  __shared__ float red[4];
  int wid = t >> 6, lane = t & 63;
  if (lane == 0) { red[wid] = s; red[2 + wid] = s2; }
  __syncthreads();
  float mean = (red[0] + red[1]) * (1.0f / HDIM);
  float var  = (red[2] + red[3]) * (1.0f / HDIM) - mean * mean;
  float rstd = rsqrtf(var + 1e-5f);
  float4 w1 = ((const float4*)w)[2 * t], w2 = ((const float4*)w)[2 * t + 1];
  float4 b1 = ((const float4*)b)[2 * t], b2 = ((const float4*)b)[2 * t + 1];
  float wv[8] = {w1.x, w1.y, w1.z, w1.w, w2.x, w2.y, w2.z, w2.w};
  float bv[8] = {b1.x, b1.y, b1.z, b1.w, b2.x, b2.y, b2.z, b2.w};
  f16x8 o;
#pragma unroll
  for (int i = 0; i < 8; i++) o[i] = (f16)((v[i] - mean) * rstd * wv[i] + bv[i]);
  ((f16x8*)(out + (size_t)row * HDIM))[t] = o;
}

// -------- GEMM: C[M,N] = act(A[M,K] @ BT[N,K]^T + bias) (+f16 resid) --------
// R4: block tile 256x256, 4 waves at 128x128 each (acc in AGPRs, 1 wave/SIMD).
// MAC per LDS byte doubles vs 64x64 waves (32 vs 16) -- the R3 bottleneck.
// Double-buffered LDS (2 x 32KB): prefetch of k+1 issued before compute so
// the vmcnt(0) barrier drain overlaps the MFMA phase.
// MODE: 0=none 2=silu 3=ug-split. XCD-banded 1-D grid swizzle.
template <int MODE, int RESID, int OUTF16>
__global__ __launch_bounds__(256, 1) void gemm_bt(const f16* __restrict__ A,
                                                  const f16* __restrict__ BT,
                                                  const float* __restrict__ bias,
                                                  const float* __restrict__ bias2,
                                                  const f16* __restrict__ resid,
                                                  void* __restrict__ Cout,
                                                  void* __restrict__ Cout2,
                                                  int M, int N, int K) {
  __shared__ __align__(16) f16 As[2][256 * 32];
  __shared__ __align__(16) f16 Bs[2][256 * 32];
  const int tid  = threadIdx.x;
  const int lane = tid & 63, wid = tid >> 6;
  const int wm = wid >> 1, wn = wid & 1;
  const int quad = lane >> 4, l16 = lane & 15;

  // XCD-banded swizzle over 256x256 tiles
  const int nbx = N >> 8, nby = M >> 8;
  const int b = blockIdx.x;
  const int xcd = b & 7;
  const int i = b >> 3;
  const int strips = nby >> 3;           // row strips per XCD
  const int rs = i / nbx, cb = i - rs * nbx;
  const long m0 = (long)(xcd * strips + rs) << 8;
  const long n0 = (long)cb << 8;

  // staging coords: tile row stride 64B = 4 chunks of 16B
  const int srow = wid * 16 + (lane >> 2);    // +64 per round
  const int scol = (lane & 3) * 8;            // element col within BK
  const f16* gA = A  + (m0 + srow) * K + scol;
  const f16* gB = BT + (n0 + srow) * K + scol;
  const int sdst = wid * 1024;                // wave-uniform byte offset (+4096/round)

  f32x4 zero = {0.f, 0.f, 0.f, 0.f};
  f32x4 acc[8][8];
#pragma unroll
  for (int i2 = 0; i2 < 8; i2++)
#pragma unroll
    for (int j = 0; j < 8; j++) acc[i2][j] = zero;

  // prologue: stage k0=0 into buffer 0
#pragma unroll
  for (int it = 0; it < 4; ++it) {
    __builtin_amdgcn_global_load_lds(AS1(gA + (size_t)(it * 64) * K),
                                     AS3((char*)As[0] + it * 4096 + sdst), 16, 0, 0);
    __builtin_amdgcn_global_load_lds(AS1(gB + (size_t)(it * 64) * K),
                                     AS3((char*)Bs[0] + it * 4096 + sdst), 16, 0, 0);
  }
  __syncthreads();

  for (int k0 = 0; k0 < K; k0 += 32) {
    const int cur = (k0 >> 5) & 1;
    // prefetch next tile into the other buffer (drained by end-of-iter barrier)
    if (k0 + 32 < K) {
      const int nxt = cur ^ 1;
#pragma unroll
      for (int it = 0; it < 4; ++it) {
        __builtin_amdgcn_global_load_lds(AS1(gA + (size_t)(it * 64) * K + (k0 + 32)),
                                         AS3((char*)As[nxt] + it * 4096 + sdst), 16, 0, 0);
        __builtin_amdgcn_global_load_lds(AS1(gB + (size_t)(it * 64) * K + (k0 + 32)),
                                         AS3((char*)Bs[nxt] + it * 4096 + sdst), 16, 0, 0);
      }
    }
    f16x8 af[8], bfr[8];
#pragma unroll
    for (int mi = 0; mi < 8; ++mi)
      af[mi] = *(const f16x8*)(As[cur] + (wm * 128 + mi * 16 + l16) * 32 + quad * 8);
#pragma unroll
    for (int ni = 0; ni < 8; ++ni)
      bfr[ni] = *(const f16x8*)(Bs[cur] + (wn * 128 + ni * 16 + l16) * 32 + quad * 8);
#pragma unroll
    for (int mi = 0; mi < 8; ++mi)
#pragma unroll
      for (int ni = 0; ni < 8; ++ni)
        acc[mi][ni] = __builtin_amdgcn_mfma_f32_16x16x32_f16(af[mi], bfr[ni], acc[mi][ni], 0, 0, 0);
    __syncthreads();
  }

  // epilogue: C/D layout col=lane&15, row=quad*4+reg
#pragma unroll
  for (int mi = 0; mi < 8; ++mi) {
#pragma unroll
    for (int ni = 0; ni < 8; ++ni) {
      const long col = n0 + wn * 128 + ni * 16 + l16;
      float bc;
      if (MODE == 3) bc = (col < HDIM) ? bias[col] : bias2[col - HDIM];
      else           bc = bias[col];
#pragma unroll
      for (int r = 0; r < 4; ++r) {
        const long row = m0 + wm * 128 + mi * 16 + quad * 4 + r;
        float v = acc[mi][ni][r] + bc;
        if (MODE == 2) v = v / (1.f + __expf(-v));
        if (MODE == 3) {
          if (col < HDIM) {
            ((f16*)Cout)[row * HDIM + col] = (f16)v;
          } else {
            float g = 1.f / (1.f + __expf(-v));
            ((f16*)Cout2)[row * HDIM + (col - HDIM)] = (f16)g;
          }
        } else {
          if (RESID) v += (float)resid[row * N + col];
          if (OUTF16) ((f16*)Cout)[row * N + col] = (f16)v;
          else        ((float*)Cout)[row * N + col] = v;
        }
      }
    }
  }
}

// -------- scan pass 1: per-chunk local fwd & bwd carries (one read pass) ----
__global__ __launch_bounds__(256) void scan_p1(const f16* __restrict__ u,
                                               const float* __restrict__ sdecay,
                                               float* __restrict__ carry_f,
                                               float* __restrict__ carry_b) {
  int tid = blockIdx.x * 256 + threadIdx.x;
  int h = tid & (HDIM - 1);
  int c = tid >> 10;
  float d = 1.f / (1.f + expf(-sdecay[h]));
  const f16* up = u + (size_t)c * CH * HDIM + h;
  float sf = 0.f, sb = 0.f, p = 1.f;
#pragma unroll
  for (int i = 0; i < CH; i++) {
    float uu = (float)up[i * HDIM];
    sf = d * sf + uu;   // local fwd final
    sb += p * uu;       // local bwd final = sum d^i * u_i
    p *= d;
  }
  carry_f[(size_t)c * HDIM + h] = sf;
  carry_b[(size_t)c * HDIM + h] = sb;
}

// -------- scan pass 2: chunk-level exclusive scans (fwd dir=0, bwd dir=1) --
__global__ __launch_bounds__(256) void scan_p2(const float* __restrict__ sdecay,
                                               const float* __restrict__ carry_f,
                                               const float* __restrict__ carry_b,
                                               float* __restrict__ cin_f,
                                               float* __restrict__ cin_b) {
  int tid = blockIdx.x * 256 + threadIdx.x;  // 2048 threads
  int h = tid & (HDIM - 1);
  int dir = tid >> 10;
  float d = 1.f / (1.f + expf(-sdecay[h]));
  float dT = powf(d, (float)CH);
  float S = 0.f;
  if (dir == 0) {
#pragma unroll 4
    for (int c = 0; c < NC; c++) {
      cin_f[(size_t)c * HDIM + h] = S;
      S = dT * S + carry_f[(size_t)c * HDIM + h];
    }
  } else {
#pragma unroll 4
    for (int c = NC - 1; c >= 0; c--) {
      cin_b[(size_t)c * HDIM + h] = S;
      S = dT * S + carry_b[(size_t)c * HDIM + h];
    }
  }
}

// -------- scan pass 3: re-scan chunk with carries, fuse gate, f16 out ------
__global__ __launch_bounds__(256) void scan_p3(const f16* __restrict__ u,
                                               const f16* __restrict__ gate,
                                               const float* __restrict__ sdecay,
                                               const float* __restrict__ cin_f,
                                               const float* __restrict__ cin_b,
                                               f16* __restrict__ state_out) {
  int tid = blockIdx.x * 256 + threadIdx.x;
  int h = tid & (HDIM - 1);
  int c = tid >> 10;
  float d = 1.f / (1.f + expf(-sdecay[h]));
  const f16* up = u    + (size_t)c * CH * HDIM + h;
  const f16* gp = gate + (size_t)c * CH * HDIM + h;
  f16* op = state_out  + (size_t)c * CH * HDIM + h;
  float ur[CH], sf[CH];
#pragma unroll
  for (int i = 0; i < CH; i++) ur[i] = (float)up[i * HDIM];
  float s = cin_f[(size_t)c * HDIM + h];
#pragma unroll
  for (int i = 0; i < CH; i++) { s = d * s + ur[i]; sf[i] = s; }
  s = cin_b[(size_t)c * HDIM + h];
#pragma unroll
  for (int i = CH - 1; i >= 0; i--) {
    s = d * s + ur[i];
    float g = (float)gp[i * HDIM];
    op[i * HDIM] = (f16)(0.5f * (sf[i] + s) * g);
  }
}

extern "C" void kernel_launch(void* const* d_in, const int* in_sizes, int n_in,
                              void* d_out, int out_size, void* d_ws, size_t ws_size,
                              hipStream_t stream) {
  const float* x      = (const float*)d_in[0];
  const float* ln1_w  = (const float*)d_in[1];
  const float* ln1_b  = (const float*)d_in[2];
  const float* W_in   = (const float*)d_in[3];
  const float* b_in   = (const float*)d_in[4];
  const float* W_gate = (const float*)d_in[5];
  const float* b_gate = (const float*)d_in[6];
  const float* W_out  = (const float*)d_in[7];
  const float* b_out  = (const float*)d_in[8];
  const float* sdecay = (const float*)d_in[9];
  const float* ln2_w  = (const float*)d_in[10];
  const float* ln2_b  = (const float*)d_in[11];
  const float* W_ff1  = (const float*)d_in[12];
  const float* b_ff1  = (const float*)d_in[13];
  const float* W_ff2  = (const float*)d_in[14];
  const float* b_ff2  = (const float*)d_in[15];
  float* out = (float*)d_out;

  char* ws = (char*)d_ws;
  const size_t MB32 = 33554432, MB64 = 67108864;
  f16* hidden = (f16*)(ws);                 // 32MB; reused as state_out
  f16* xh     = (f16*)(ws + MB32);          // 32MB f16 copy of x
  f16* u      = (f16*)(ws + 2 * MB32);      // 32MB; reused as h2
  f16* gate   = (f16*)(ws + 3 * MB32);      // 32MB
  f16* x2h    = (f16*)(ws + 4 * MB32);      // 32MB f16 x2
  f16* ff     = (f16*)(ws + 5 * MB32);      // 64MB
  char* wbase = ws + 5 * MB32 + MB64;
  f16* wt_ug  = (f16*)(wbase);                       // 4MB (2048x1024)
  f16* wt_out = (f16*)(wbase + 4194304);             // 2MB
  f16* wt_ff1 = (f16*)(wbase + 4194304 + 2097152);   // 4MB
  f16* wt_ff2 = (f16*)(wbase + 2 * 4194304 + 2097152); // 4MB
  char* cbase = wbase + 3 * 4194304 + 2097152;
  float* carry_f = (float*)(cbase);
  float* carry_b = (float*)(cbase + 2097152);
  float* cin_f   = (float*)(cbase + 2 * 2097152);
  float* cin_b   = (float*)(cbase + 3 * 2097152);
  f16* state_out = hidden;  // hidden dead after fused u/gate GEMM
  f16* h2        = u;       // u dead after scan_p3

  dim3 tb(32, 8);
  wcvt_t<<<dim3(32, 32), tb, 0, stream>>>(W_in,   wt_ug,                 1024, 1024);
  wcvt_t<<<dim3(32, 32), tb, 0, stream>>>(W_gate, wt_ug + 1024 * 1024,   1024, 1024);
  wcvt_t<<<dim3(32, 32), tb, 0, stream>>>(W_out,  wt_out,                1024, 1024);
  wcvt_t<<<dim3(64, 32), tb, 0, stream>>>(W_ff1,  wt_ff1,                1024, 2048);
  wcvt_t<<<dim3(32, 64), tb, 0, stream>>>(W_ff2,  wt_ff2,                2048, 1024);

  ln_k<<<L_SEQ, 256, 0, stream>>>(x, ln1_w, ln1_b, hidden, xh);

  // fused u + gate: N=2048, split epilogue  (64x8 = 512 tiles of 256x256)
  gemm_bt<3, 0, 1><<<512, 256, 0, stream>>>(hidden, wt_ug, b_in, b_gate, nullptr,
                                            u, gate, L_SEQ, 2048, 1024);

  scan_p1<<<2048, 256, 0, stream>>>(u, sdecay, carry_f, carry_b);
  scan_p2<<<8, 256, 0, stream>>>(sdecay, carry_f, carry_b, cin_f, cin_b);
  scan_p3<<<2048, 256, 0, stream>>>(u, gate, sdecay, cin_f, cin_b, state_out);

  // x2 = x + state_out @ W_out + b_out  (f16 out)  (64x4 = 256 tiles)
  gemm_bt<0, 1, 1><<<256, 256, 0, stream>>>(state_out, wt_out, b_out, nullptr, xh,
                                            x2h, nullptr, L_SEQ, 1024, 1024);

  ln_k16<<<L_SEQ, 128, 0, stream>>>(x2h, ln2_w, ln2_b, h2);

  gemm_bt<2, 0, 1><<<512, 256, 0, stream>>>(h2, wt_ff1, b_ff1, nullptr, nullptr,
                                            ff, nullptr, L_SEQ, 2048, 1024);

  // out = x2 + silu(h2@W_ff1) @ W_ff2 + b_ff2  (fp32 out)  (64x4 = 256 tiles)
  gemm_bt<0, 1, 0><<<256, 256, 0, stream>>>(ff, wt_ff2, b_ff2, nullptr, x2h,
                                            out, nullptr, L_SEQ, 1024, 2048);
}

// Round 5
// 595.631 us; speedup vs baseline: 1.3383x; 1.3383x over previous
//
#include <hip/hip_runtime.h>
#include <hip/hip_bf16.h>
#include <hip/hip_fp16.h>

#define L_SEQ 16384
#define HDIM  1024
#define CH    32
#define NC    (L_SEQ / CH)   // 512 chunks

typedef _Float16 f16;
typedef _Float16 f16x8 __attribute__((ext_vector_type(8)));
typedef _Float16 f16x4 __attribute__((ext_vector_type(4)));
typedef float    f32x4 __attribute__((ext_vector_type(4)));

#define AS1(p) (const __attribute__((address_space(1))) void*)(p)
#define AS3(p) (__attribute__((address_space(3))) void*)(p)

// -------- weight convert + transpose: out[n*K+k] = (f16) in[k*N+n] --------
__global__ __launch_bounds__(256) void wcvt_t(const float* __restrict__ in,
                                              f16* __restrict__ out, int K, int N) {
  __shared__ float tile[32][33];
  int n0 = blockIdx.x * 32, k0 = blockIdx.y * 32;
  int tx = threadIdx.x, ty = threadIdx.y;  // (32,8)
#pragma unroll
  for (int i = 0; i < 4; i++) {
    int k = k0 + ty + i * 8;
    tile[ty + i * 8][tx] = in[(size_t)k * N + n0 + tx];
  }
  __syncthreads();
#pragma unroll
  for (int i = 0; i < 4; i++) {
    int n = n0 + ty + i * 8;
    out[(size_t)n * K + k0 + tx] = (f16)tile[tx][ty + i * 8];
  }
}

// -------- LayerNorm fp32 in -> f16 out (+ optional f16 copy of input) -----
__global__ __launch_bounds__(256) void ln_k(const float* __restrict__ x,
                                            const float* __restrict__ w,
                                            const float* __restrict__ b,
                                            f16* __restrict__ out,
                                            f16* __restrict__ xcopy) {
  int row = blockIdx.x;
  int t = threadIdx.x;
  const float4* xr = (const float4*)(x + (size_t)row * HDIM);
  float4 v = xr[t];
  float s  = v.x + v.y + v.z + v.w;
  float s2 = v.x * v.x + v.y * v.y + v.z * v.z + v.w * v.w;
#pragma unroll
  for (int off = 32; off > 0; off >>= 1) {
    s  += __shfl_down(s, off);
    s2 += __shfl_down(s2, off);
  }
  __shared__ float red[8];
  int wid = t >> 6, lane = t & 63;
  if (lane == 0) { red[wid] = s; red[4 + wid] = s2; }
  __syncthreads();
  if (t == 0) {
    red[0] = red[0] + red[1] + red[2] + red[3];
    red[4] = red[4] + red[5] + red[6] + red[7];
  }
  __syncthreads();
  float mean = red[0] * (1.0f / HDIM);
  float var  = red[4] * (1.0f / HDIM) - mean * mean;
  float rstd = rsqrtf(var + 1e-5f);
  float4 ww = ((const float4*)w)[t];
  float4 bb = ((const float4*)b)[t];
  f16x4 o;
  o[0] = (f16)((v.x - mean) * rstd * ww.x + bb.x);
  o[1] = (f16)((v.y - mean) * rstd * ww.y + bb.y);
  o[2] = (f16)((v.z - mean) * rstd * ww.z + bb.z);
  o[3] = (f16)((v.w - mean) * rstd * ww.w + bb.w);
  ((f16x4*)(out + (size_t)row * HDIM))[t] = o;
  if (xcopy) {
    f16x4 c;
    c[0] = (f16)v.x; c[1] = (f16)v.y; c[2] = (f16)v.z; c[3] = (f16)v.w;
    ((f16x4*)(xcopy + (size_t)row * HDIM))[t] = c;
  }
}

// -------- LayerNorm f16 in -> f16 out, 128 thr/row, f16x8 loads --------
__global__ __launch_bounds__(128) void ln_k16(const f16* __restrict__ x,
                                              const float* __restrict__ w,
                                              const float* __restrict__ b,
                                              f16* __restrict__ out) {
  int row = blockIdx.x;
  int t = threadIdx.x;  // 0..127
  f16x8 xv = ((const f16x8*)(x + (size_t)row * HDIM))[t];
  float v[8];
  float s = 0.f, s2 = 0.f;
#pragma unroll
  for (int i = 0; i < 8; i++) {
    v[i] = (float)xv[i];
    s += v[i]; s2 += v[i] * v[i];
  }
#pragma unroll
  for (int off = 32; off > 0; off >>= 1) {
    s  += __shfl_down(s, off);
    s2 += __shfl_down(s2, off);
  }
  __shared__ float red[4];
  int wid = t >> 6, lane = t & 63;
  if (lane == 0) { red[wid] = s; red[2 + wid] = s2; }
  __syncthreads();
  float mean = (red[0] + red[1]) * (1.0f / HDIM);
  float var  = (red[2] + red[3]) * (1.0f / HDIM) - mean * mean;
  float rstd = rsqrtf(var + 1e-5f);
  float4 w1 = ((const float4*)w)[2 * t], w2 = ((const float4*)w)[2 * t + 1];
  float4 b1 = ((const float4*)b)[2 * t], b2 = ((const float4*)b)[2 * t + 1];
  float wv[8] = {w1.x, w1.y, w1.z, w1.w, w2.x, w2.y, w2.z, w2.w};
  float bv[8] = {b1.x, b1.y, b1.z, b1.w, b2.x, b2.y, b2.z, b2.w};
  f16x8 o;
#pragma unroll
  for (int i = 0; i < 8; i++) o[i] = (f16)((v[i] - mean) * rstd * wv[i] + bv[i]);
  ((f16x8*)(out + (size_t)row * HDIM))[t] = o;
}

// -------- GEMM: C[M,N] = act(A[M,K] @ BT[N,K]^T + bias) (+f16 resid) --------
// R5: 128x128 block, 4 waves 64x64 (modest VGPR -> 4 waves/SIMD, the R3
// occupancy), PLUS double-buffered LDS (2x16KB) with prefetch issued BEFORE
// compute and ONE barrier per k-iter. The R3 limiter was cold DMA latency
// exposed at each barrier; here ~200+ cyc of mfma/ds_read from 16 resident
// waves cover the DMA before the vmcnt(0) drain.
// MODE: 0=none 2=silu 3=ug-split. XCD-banded 1-D grid swizzle.
template <int MODE, int RESID, int OUTF16>
__global__ __launch_bounds__(256, 4) void gemm_bt(const f16* __restrict__ A,
                                                  const f16* __restrict__ BT,
                                                  const float* __restrict__ bias,
                                                  const float* __restrict__ bias2,
                                                  const f16* __restrict__ resid,
                                                  void* __restrict__ Cout,
                                                  void* __restrict__ Cout2,
                                                  int M, int N, int K) {
  __shared__ __align__(16) f16 As[2][128 * 32];
  __shared__ __align__(16) f16 Bs[2][128 * 32];
  const int tid  = threadIdx.x;
  const int lane = tid & 63, wid = tid >> 6;
  const int wm = wid >> 1, wn = wid & 1;
  const int quad = lane >> 4, l16 = lane & 15;

  // XCD-banded swizzle over 128x128 tiles
  const int nbx = N >> 7, nby = M >> 7;
  const int b = blockIdx.x;
  const int xcd = b & 7;
  const int i = b >> 3;
  const int strips = nby >> 3;           // row strips per XCD
  const int rs = i / nbx, cb = i - rs * nbx;
  const long m0 = (long)(xcd * strips + rs) << 7;
  const long n0 = (long)cb << 7;

  // staging coords: row stride 64B (32 f16); 256 thr x 16B = 4KB per round
  const int srow = wid * 16 + (lane >> 2);   // + 64 per round (it)
  const int scol = (lane & 3) * 8;
  const f16* gA = A  + (m0 + srow) * K + scol;
  const f16* gB = BT + (n0 + srow) * K + scol;
  const int sdst = wid * 1024;               // + 4096 per round (wave-uniform)

  f32x4 zero = {0.f, 0.f, 0.f, 0.f};
  f32x4 acc[4][4];
#pragma unroll
  for (int i2 = 0; i2 < 4; i2++)
#pragma unroll
    for (int j = 0; j < 4; j++) acc[i2][j] = zero;

  // prologue: stage k0=0 into buffer 0
#pragma unroll
  for (int it = 0; it < 2; ++it) {
    __builtin_amdgcn_global_load_lds(AS1(gA + (size_t)(it * 64) * K),
                                     AS3((char*)As[0] + it * 4096 + sdst), 16, 0, 0);
    __builtin_amdgcn_global_load_lds(AS1(gB + (size_t)(it * 64) * K),
                                     AS3((char*)Bs[0] + it * 4096 + sdst), 16, 0, 0);
  }
  __syncthreads();

  const int niter = K >> 5;
  for (int ki = 0; ki < niter; ++ki) {
    const int cur = ki & 1;
    // prefetch k+1 into the other buffer (safe: barrier at end of prev iter
    // guaranteed all waves finished reading it)
    if (ki + 1 < niter) {
      const int nxt = cur ^ 1;
      const int koff = (ki + 1) << 5;
#pragma unroll
      for (int it = 0; it < 2; ++it) {
        __builtin_amdgcn_global_load_lds(AS1(gA + (size_t)(it * 64) * K + koff),
                                         AS3((char*)As[nxt] + it * 4096 + sdst), 16, 0, 0);
        __builtin_amdgcn_global_load_lds(AS1(gB + (size_t)(it * 64) * K + koff),
                                         AS3((char*)Bs[nxt] + it * 4096 + sdst), 16, 0, 0);
      }
    }
    f16x8 af[4], bfr[4];
#pragma unroll
    for (int mi = 0; mi < 4; ++mi)
      af[mi] = *(const f16x8*)(As[cur] + (wm * 64 + mi * 16 + l16) * 32 + quad * 8);
#pragma unroll
    for (int ni = 0; ni < 4; ++ni)
      bfr[ni] = *(const f16x8*)(Bs[cur] + (wn * 64 + ni * 16 + l16) * 32 + quad * 8);
#pragma unroll
    for (int mi = 0; mi < 4; ++mi)
#pragma unroll
      for (int ni = 0; ni < 4; ++ni)
        acc[mi][ni] = __builtin_amdgcn_mfma_f32_16x16x32_f16(af[mi], bfr[ni], acc[mi][ni], 0, 0, 0);
    // one barrier per iter: drains prefetch DMA (overlapped by compute above)
    // and protects cur buffer from being overwritten next iter
    __syncthreads();
  }

  // epilogue: C/D layout col=lane&15, row=quad*4+reg
#pragma unroll
  for (int mi = 0; mi < 4; ++mi) {
#pragma unroll
    for (int ni = 0; ni < 4; ++ni) {
      const long col = n0 + wn * 64 + ni * 16 + l16;
      float bc;
      if (MODE == 3) bc = (col < HDIM) ? bias[col] : bias2[col - HDIM];
      else           bc = bias[col];
#pragma unroll
      for (int r = 0; r < 4; ++r) {
        const long row = m0 + wm * 64 + mi * 16 + quad * 4 + r;
        float v = acc[mi][ni][r] + bc;
        if (MODE == 2) v = v / (1.f + __expf(-v));
        if (MODE == 3) {
          if (col < HDIM) {
            ((f16*)Cout)[row * HDIM + col] = (f16)v;
          } else {
            float g = 1.f / (1.f + __expf(-v));
            ((f16*)Cout2)[row * HDIM + (col - HDIM)] = (f16)g;
          }
        } else {
          if (RESID) v += (float)resid[row * N + col];
          if (OUTF16) ((f16*)Cout)[row * N + col] = (f16)v;
          else        ((float*)Cout)[row * N + col] = v;
        }
      }
    }
  }
}

// -------- scan pass 1: per-chunk local fwd & bwd carries (one read pass) ----
__global__ __launch_bounds__(256) void scan_p1(const f16* __restrict__ u,
                                               const float* __restrict__ sdecay,
                                               float* __restrict__ carry_f,
                                               float* __restrict__ carry_b) {
  int tid = blockIdx.x * 256 + threadIdx.x;
  int h = tid & (HDIM - 1);
  int c = tid >> 10;
  float d = 1.f / (1.f + expf(-sdecay[h]));
  const f16* up = u + (size_t)c * CH * HDIM + h;
  float sf = 0.f, sb = 0.f, p = 1.f;
#pragma unroll
  for (int i = 0; i < CH; i++) {
    float uu = (float)up[i * HDIM];
    sf = d * sf + uu;   // local fwd final
    sb += p * uu;       // local bwd final = sum d^i * u_i
    p *= d;
  }
  carry_f[(size_t)c * HDIM + h] = sf;
  carry_b[(size_t)c * HDIM + h] = sb;
}

// -------- scan pass 2: chunk-level exclusive scans (fwd dir=0, bwd dir=1) --
__global__ __launch_bounds__(256) void scan_p2(const float* __restrict__ sdecay,
                                               const float* __restrict__ carry_f,
                                               const float* __restrict__ carry_b,
                                               float* __restrict__ cin_f,
                                               float* __restrict__ cin_b) {
  int tid = blockIdx.x * 256 + threadIdx.x;  // 2048 threads
  int h = tid & (HDIM - 1);
  int dir = tid >> 10;
  float d = 1.f / (1.f + expf(-sdecay[h]));
  float dT = powf(d, (float)CH);
  float S = 0.f;
  if (dir == 0) {
#pragma unroll 4
    for (int c = 0; c < NC; c++) {
      cin_f[(size_t)c * HDIM + h] = S;
      S = dT * S + carry_f[(size_t)c * HDIM + h];
    }
  } else {
#pragma unroll 4
    for (int c = NC - 1; c >= 0; c--) {
      cin_b[(size_t)c * HDIM + h] = S;
      S = dT * S + carry_b[(size_t)c * HDIM + h];
    }
  }
}

// -------- scan pass 3: re-scan chunk with carries, fuse gate, f16 out ------
__global__ __launch_bounds__(256) void scan_p3(const f16* __restrict__ u,
                                               const f16* __restrict__ gate,
                                               const float* __restrict__ sdecay,
                                               const float* __restrict__ cin_f,
                                               const float* __restrict__ cin_b,
                                               f16* __restrict__ state_out) {
  int tid = blockIdx.x * 256 + threadIdx.x;
  int h = tid & (HDIM - 1);
  int c = tid >> 10;
  float d = 1.f / (1.f + expf(-sdecay[h]));
  const f16* up = u    + (size_t)c * CH * HDIM + h;
  const f16* gp = gate + (size_t)c * CH * HDIM + h;
  f16* op = state_out  + (size_t)c * CH * HDIM + h;
  float ur[CH], sf[CH];
#pragma unroll
  for (int i = 0; i < CH; i++) ur[i] = (float)up[i * HDIM];
  float s = cin_f[(size_t)c * HDIM + h];
#pragma unroll
  for (int i = 0; i < CH; i++) { s = d * s + ur[i]; sf[i] = s; }
  s = cin_b[(size_t)c * HDIM + h];
#pragma unroll
  for (int i = CH - 1; i >= 0; i--) {
    s = d * s + ur[i];
    float g = (float)gp[i * HDIM];
    op[i * HDIM] = (f16)(0.5f * (sf[i] + s) * g);
  }
}

extern "C" void kernel_launch(void* const* d_in, const int* in_sizes, int n_in,
                              void* d_out, int out_size, void* d_ws, size_t ws_size,
                              hipStream_t stream) {
  const float* x      = (const float*)d_in[0];
  const float* ln1_w  = (const float*)d_in[1];
  const float* ln1_b  = (const float*)d_in[2];
  const float* W_in   = (const float*)d_in[3];
  const float* b_in   = (const float*)d_in[4];
  const float* W_gate = (const float*)d_in[5];
  const float* b_gate = (const float*)d_in[6];
  const float* W_out  = (const float*)d_in[7];
  const float* b_out  = (const float*)d_in[8];
  const float* sdecay = (const float*)d_in[9];
  const float* ln2_w  = (const float*)d_in[10];
  const float* ln2_b  = (const float*)d_in[11];
  const float* W_ff1  = (const float*)d_in[12];
  const float* b_ff1  = (const float*)d_in[13];
  const float* W_ff2  = (const float*)d_in[14];
  const float* b_ff2  = (const float*)d_in[15];
  float* out = (float*)d_out;

  char* ws = (char*)d_ws;
  const size_t MB32 = 33554432, MB64 = 67108864;
  f16* hidden = (f16*)(ws);                 // 32MB; reused as state_out
  f16* xh     = (f16*)(ws + MB32);          // 32MB f16 copy of x
  f16* u      = (f16*)(ws + 2 * MB32);      // 32MB; reused as h2
  f16* gate   = (f16*)(ws + 3 * MB32);      // 32MB
  f16* x2h    = (f16*)(ws + 4 * MB32);      // 32MB f16 x2
  f16* ff     = (f16*)(ws + 5 * MB32);      // 64MB
  char* wbase = ws + 5 * MB32 + MB64;
  f16* wt_ug  = (f16*)(wbase);                       // 4MB (2048x1024)
  f16* wt_out = (f16*)(wbase + 4194304);             // 2MB
  f16* wt_ff1 = (f16*)(wbase + 4194304 + 2097152);   // 4MB
  f16* wt_ff2 = (f16*)(wbase + 2 * 4194304 + 2097152); // 4MB
  char* cbase = wbase + 3 * 4194304 + 2097152;
  float* carry_f = (float*)(cbase);
  float* carry_b = (float*)(cbase + 2097152);
  float* cin_f   = (float*)(cbase + 2 * 2097152);
  float* cin_b   = (float*)(cbase + 3 * 2097152);
  f16* state_out = hidden;  // hidden dead after fused u/gate GEMM
  f16* h2        = u;       // u dead after scan_p3

  dim3 tb(32, 8);
  wcvt_t<<<dim3(32, 32), tb, 0, stream>>>(W_in,   wt_ug,                 1024, 1024);
  wcvt_t<<<dim3(32, 32), tb, 0, stream>>>(W_gate, wt_ug + 1024 * 1024,   1024, 1024);
  wcvt_t<<<dim3(32, 32), tb, 0, stream>>>(W_out,  wt_out,                1024, 1024);
  wcvt_t<<<dim3(64, 32), tb, 0, stream>>>(W_ff1,  wt_ff1,                1024, 2048);
  wcvt_t<<<dim3(32, 64), tb, 0, stream>>>(W_ff2,  wt_ff2,                2048, 1024);

  ln_k<<<L_SEQ, 256, 0, stream>>>(x, ln1_w, ln1_b, hidden, xh);

  // fused u + gate: N=2048, split epilogue  (128x16 = 2048 tiles of 128x128)
  gemm_bt<3, 0, 1><<<2048, 256, 0, stream>>>(hidden, wt_ug, b_in, b_gate, nullptr,
                                             u, gate, L_SEQ, 2048, 1024);

  scan_p1<<<2048, 256, 0, stream>>>(u, sdecay, carry_f, carry_b);
  scan_p2<<<8, 256, 0, stream>>>(sdecay, carry_f, carry_b, cin_f, cin_b);
  scan_p3<<<2048, 256, 0, stream>>>(u, gate, sdecay, cin_f, cin_b, state_out);

  // x2 = x + state_out @ W_out + b_out  (f16 out)  (128x8 = 1024 tiles)
  gemm_bt<0, 1, 1><<<1024, 256, 0, stream>>>(state_out, wt_out, b_out, nullptr, xh,
                                             x2h, nullptr, L_SEQ, 1024, 1024);

  ln_k16<<<L_SEQ, 128, 0, stream>>>(x2h, ln2_w, ln2_b, h2);

  gemm_bt<2, 0, 1><<<2048, 256, 0, stream>>>(h2, wt_ff1, b_ff1, nullptr, nullptr,
                                             ff, nullptr, L_SEQ, 2048, 1024);

  // out = x2 + silu(h2@W_ff1) @ W_ff2 + b_ff2  (fp32 out)  (128x8 = 1024 tiles)
  gemm_bt<0, 1, 0><<<1024, 256, 0, stream>>>(ff, wt_ff2, b_ff2, nullptr, x2h,
                                             out, nullptr, L_SEQ, 1024, 2048);
}